// Round 1
// baseline (763.732 us; speedup 1.0000x reference)
//
#include <hip/hip_runtime.h>

// ---------------------------------------------------------------------------
// CausalLinearAttentionRSEEncoder: full block implementation
// B=4 T=2048 D=1024 H=16 K=64 BK=32 FFN=4096 LORA=48 CHUNK=64 NC=32
// ---------------------------------------------------------------------------

typedef __bf16 bf16x8 __attribute__((ext_vector_type(8)));
typedef float f32x4 __attribute__((ext_vector_type(4)));

__device__ __forceinline__ unsigned short f2bf(float f) {
  unsigned int u = __builtin_bit_cast(unsigned int, f);
  u += 0x7FFFu + ((u >> 16) & 1u);
  return (unsigned short)(u >> 16);
}

__device__ __forceinline__ float rlane(float v, int l) {
  return __builtin_bit_cast(float, __builtin_amdgcn_readlane(__builtin_bit_cast(int, v), l));
}

__device__ __forceinline__ void gload_lds16(const void* g, void* l) {
  __builtin_amdgcn_global_load_lds((const __attribute__((address_space(1))) void*)g,
                                   (__attribute__((address_space(3))) void*)l, 16, 0, 0);
}

__device__ __forceinline__ float gelu_tanh(float v) {
  float c = fmaf(0.044715f * v * v, v, v);
  return 0.5f * v * (1.f + tanhf(0.7978845608028654f * c));
}

// -------------------------------- fill (ws guard) ---------------------------
__global__ void fill_kernel(float* p, float v, int n) {
  int i = blockIdx.x * 256 + threadIdx.x;
  if (i < n) p[i] = v;
}

// -------------------------------- LayerNorm -> bf16 -------------------------
__global__ __launch_bounds__(256) void ln_kernel(
    const float* __restrict__ x, const float* __restrict__ g,
    const float* __restrict__ b, unsigned short* __restrict__ out) {
  const int row = blockIdx.x, tid = threadIdx.x;
  float4 v = ((const float4*)(x + (size_t)row * 1024))[tid];
  float s = v.x + v.y + v.z + v.w;
  float sq = v.x * v.x + v.y * v.y + v.z * v.z + v.w * v.w;
#pragma unroll
  for (int o = 32; o > 0; o >>= 1) { s += __shfl_xor(s, o); sq += __shfl_xor(sq, o); }
  __shared__ float red[8];
  const int wid = tid >> 6;
  if ((tid & 63) == 0) { red[wid] = s; red[4 + wid] = sq; }
  __syncthreads();
  s = red[0] + red[1] + red[2] + red[3];
  sq = red[4] + red[5] + red[6] + red[7];
  const float mean = s * (1.f / 1024.f);
  const float var = sq * (1.f / 1024.f) - mean * mean;
  const float rstd = rsqrtf(var + 1e-6f);
  float4 gv = ((const float4*)g)[tid];
  float4 bvv = ((const float4*)b)[tid];
  ushort4 o4;
  o4.x = f2bf((v.x - mean) * rstd * gv.x + bvv.x);
  o4.y = f2bf((v.y - mean) * rstd * gv.y + bvv.y);
  o4.z = f2bf((v.z - mean) * rstd * gv.z + bvv.z);
  o4.w = f2bf((v.w - mean) * rstd * gv.w + bvv.w);
  *(ushort4*)(out + (size_t)row * 1024 + tid * 4) = o4;
}

// ------------------------- weight transposes to bf16 ------------------------
// dst[n][k] = src[k][n]; grid (N/32, K/32), block (32,8)
__global__ __launch_bounds__(256) void transpose_bf16(
    const float* __restrict__ src, unsigned short* __restrict__ dst, int K, int N) {
  __shared__ float tile[32][33];
  const int n0 = blockIdx.x * 32, k0 = blockIdx.y * 32;
  const int tx = threadIdx.x, ty = threadIdx.y;
#pragma unroll
  for (int j = 0; j < 32; j += 8) tile[tx][ty + j] = src[(size_t)(k0 + ty + j) * N + n0 + tx];
  __syncthreads();
#pragma unroll
  for (int j = 0; j < 32; j += 8)
    dst[(size_t)(n0 + ty + j) * K + k0 + tx] = f2bf(tile[ty + j][tx]);
}

// WcatT[3200][1024]: rows 0..1023 Wq^T | 1024..2047 Wk^T | 2048..3071 Wv^T |
// 3072..3119 theta_w1^T | 3120..3199 zero.  grid (100, 32), block (32,8)
__global__ __launch_bounds__(256) void prep_wcat(
    const float* __restrict__ Wq, const float* __restrict__ Wk,
    const float* __restrict__ Wv, const float* __restrict__ tw1,
    unsigned short* __restrict__ dst) {
  __shared__ float tile[32][33];
  const int r0 = blockIdx.x * 32, c0 = blockIdx.y * 32;
  const int tx = threadIdx.x, ty = threadIdx.y;
  const int r = r0 + tx;
#pragma unroll
  for (int j = 0; j < 32; j += 8) {
    const int c = c0 + ty + j;
    float v;
    if (r < 1024) v = Wq[(size_t)c * 1024 + r];
    else if (r < 2048) v = Wk[(size_t)c * 1024 + (r - 1024)];
    else if (r < 3072) v = Wv[(size_t)c * 1024 + (r - 2048)];
    else if (r < 3120) v = tw1[(size_t)c * 48 + (r - 3072)];
    else v = 0.f;
    tile[tx][ty + j] = v;
  }
  __syncthreads();
#pragma unroll
  for (int j = 0; j < 32; j += 8)
    dst[(size_t)(r0 + ty + j) * 1024 + c0 + tx] = f2bf(tile[ty + j][tx]);
}

__global__ void biascat_kernel(const float* bq, const float* bk, const float* bv, float* dst) {
  int i = blockIdx.x * 256 + threadIdx.x;
  if (i >= 3200) return;
  float v = 0.f;
  if (i < 1024) v = bq[i];
  else if (i < 2048) v = bk[i - 1024];
  else if (i < 3072) v = bv[i - 2048];
  dst[i] = v;
}

// ------------------------------- bf16 MFMA GEMM -----------------------------
// C[M][N] = A[M][Kd](bf16) @ BT[N][Kd](bf16)^T + bias
// MODE 0: fp32 out;  MODE 1: fp32 out + res;  MODE 2: bf16 out, gelu
template <int MODE>
__global__ __launch_bounds__(256) void gemm_kernel(
    const unsigned short* __restrict__ A, const unsigned short* __restrict__ BT,
    const float* __restrict__ bias, const float* __restrict__ res,
    void* __restrict__ out, int N, int Kd) {
  __shared__ unsigned short As[128 * 64];
  __shared__ unsigned short Bs[128 * 64];
  const int n0 = blockIdx.x * 128, m0 = blockIdx.y * 128;
  const int tid = threadIdx.x, wv = tid >> 6, ln = tid & 63;
  const int wm = wv >> 1, wn = wv & 1;
  const int l15 = ln & 15, lk = (ln >> 4) * 8;
  const int rsub = ln >> 3;          // 0..7 rows within 8-row stripe
  const int csub = (ln & 7) * 8;     // element offset along K (8 bf16 = 16B)
  f32x4 acc[4][4] = {};
  for (int k0 = 0; k0 < Kd; k0 += 64) {
#pragma unroll
    for (int jj = 0; jj < 4; ++jj) {
      const int r0 = (wv * 4 + jj) * 8;
      gload_lds16(A + (size_t)(m0 + r0 + rsub) * Kd + k0 + csub,
                  (char*)As + (wv * 4 + jj) * 1024);
      gload_lds16(BT + (size_t)(n0 + r0 + rsub) * Kd + k0 + csub,
                  (char*)Bs + (wv * 4 + jj) * 1024);
    }
    __syncthreads();
#pragma unroll
    for (int kk = 0; kk < 64; kk += 32) {
      bf16x8 av[4], bv[4];
#pragma unroll
      for (int f = 0; f < 4; ++f) {
        av[f] = *(const bf16x8*)&As[(wm * 64 + f * 16 + l15) * 64 + kk + lk];
        bv[f] = *(const bf16x8*)&Bs[(wn * 64 + f * 16 + l15) * 64 + kk + lk];
      }
#pragma unroll
      for (int fm = 0; fm < 4; ++fm)
#pragma unroll
        for (int fn = 0; fn < 4; ++fn)
          acc[fm][fn] = __builtin_amdgcn_mfma_f32_16x16x32_bf16(av[fm], bv[fn], acc[fm][fn], 0, 0, 0);
    }
    __syncthreads();
  }
  const int rb = (ln >> 4) * 4;
#pragma unroll
  for (int fm = 0; fm < 4; ++fm) {
#pragma unroll
    for (int fn = 0; fn < 4; ++fn) {
      const int row = m0 + wm * 64 + fm * 16 + rb;
      const int col = n0 + wn * 64 + fn * 16 + l15;
      const float bval = bias[col];
#pragma unroll
      for (int r = 0; r < 4; ++r) {
        float v = acc[fm][fn][r] + bval;
        const size_t oi = (size_t)(row + r) * N + col;
        if constexpr (MODE == 1) v += res[oi];
        if constexpr (MODE == 2) {
          ((unsigned short*)out)[oi] = f2bf(gelu_tanh(v));
        } else {
          ((float*)out)[oi] = v;
        }
      }
    }
  }
}

// -------------------------- LoRA2 + theta (clip) ----------------------------
// theta[m][hc] = clip(theta_base[hc] + sum_j tanh(lora1[m][j]) * w2[j][hc])
__global__ __launch_bounds__(256) void lora2_kernel(
    const float* __restrict__ qkv, const float* __restrict__ w2,
    const float* __restrict__ tbase, float* __restrict__ theta) {
  __shared__ float lt[8][48];
  const int m0 = blockIdx.x * 32;
  const int tid = threadIdx.x;
  const int col = tid * 2;
  const float tb0 = tbase[col], tb1 = tbase[col + 1];
  for (int grp = 0; grp < 4; ++grp) {
    const int mg = m0 + grp * 8;
    __syncthreads();
    for (int idx = tid; idx < 384; idx += 256) {
      const int tok = idx / 48, jj = idx % 48;
      lt[tok][jj] = tanhf(qkv[(size_t)(mg + tok) * 3200 + 3072 + jj]);
    }
    __syncthreads();
    float a0[8], a1[8];
#pragma unroll
    for (int tok = 0; tok < 8; ++tok) { a0[tok] = tb0; a1[tok] = tb1; }
    for (int jj = 0; jj < 48; ++jj) {
      const float2 w = *(const float2*)&w2[(size_t)jj * 512 + col];
#pragma unroll
      for (int tok = 0; tok < 8; ++tok) {
        const float l = lt[tok][jj];
        a0[tok] = fmaf(l, w.x, a0[tok]);
        a1[tok] = fmaf(l, w.y, a1[tok]);
      }
    }
    const float CL = 1.5707963267948966f;
#pragma unroll
    for (int tok = 0; tok < 8; ++tok) {
      float c0 = fminf(fmaxf(a0[tok], -CL), CL);
      float c1 = fminf(fmaxf(a1[tok], -CL), CL);
      *(float2*)&theta[(size_t)(mg + tok) * 512 + col] = make_float2(c0, c1);
    }
  }
}

// ------------------------------- pass A -------------------------------------
// Per (b,h,chunk): intra-chunk recurrence S[t]=z[t]*S[t-1]+kc[t]*v[t];
// writes y_intra, qd (=conj(q)*exp(cumlog)), T_chunk (=S[63]), D_chunk.
__global__ __launch_bounds__(64) void passA_kernel(
    const float* __restrict__ qkv, const float* __restrict__ theta,
    const float* __restrict__ lamb, const float* __restrict__ eta,
    float* __restrict__ yi, float* __restrict__ Qg,
    float* __restrict__ Tg, float* __restrict__ Dg) {
  const int c = blockIdx.x, bh = blockIdx.y;
  const int b = bh >> 4, h = bh & 15;
  const int cid = bh * 32 + c;
  const int lane = threadIdx.x;
  const int j = lane & 31;
  __shared__ float P[32][3][64];
  float Sre[32], Sim[32];
#pragma unroll
  for (int i = 0; i < 32; ++i) { Sre[i] = 0.f; Sim[i] = 0.f; }
  const int m0 = b * 2048 + c * 64;
  float lb = 0.f, et = 0.f;
  if (lane < 32) { lb = lamb[h * 32 + j]; et = eta[h * 32 + j]; }
  float cumL = 0.f, cumT = 0.f;
  float vnext = qkv[(size_t)m0 * 3200 + 2048 + h * 64 + lane];
  for (int half = 0; half < 2; ++half) {
    if (lane < 32) {
      for (int tt = 0; tt < 32; ++tt) {
        const int t = half * 32 + tt;
        const size_t m = (size_t)(m0 + t);
        const float th = theta[m * 512 + h * 32 + j];
        const float2 kp = *(const float2*)&qkv[m * 3200 + 1024 + h * 64 + 2 * j];
        const float2 qp = *(const float2*)&qkv[m * 3200 + h * 64 + 2 * j];
        const float lam = fmaf(et * th, th, lb);
        const float e = __expf(-lam);
        float sn, cs;
        __sincosf(th, &sn, &cs);
        P[tt][0][j] = e * cs;
        P[tt][1][j] = e * sn;
        P[tt][2][j] = kp.x > 0.f ? kp.x + 1.f : __expf(kp.x);
        P[tt][0][32 + j] = kp.y > 0.f ? kp.y + 1.f : __expf(kp.y);
        P[tt][1][32 + j] = qp.x;
        P[tt][2][32 + j] = qp.y;
        cumL += lam; cumT += th;
        const float de = __expf(-cumL);
        float dsn, dcs;
        __sincosf(cumT, &dsn, &dcs);
        Qg[((size_t)cid * 64 + t) * 64 + j]      = de * (qp.x * dcs + qp.y * dsn);
        Qg[((size_t)cid * 64 + t) * 64 + 32 + j] = de * (qp.x * dsn - qp.y * dcs);
      }
    }
    __syncthreads();
    for (int tt = 0; tt < 32; ++tt) {
      const int t = half * 32 + tt;
      const float vcur = vnext;
      if (t < 63) vnext = qkv[(size_t)(m0 + t + 1) * 3200 + 2048 + h * 64 + lane];
      const float p0 = P[tt][0][lane], p1 = P[tt][1][lane], p2 = P[tt][2][lane];
      float y = 0.f;
#pragma unroll
      for (int bk = 0; bk < 32; ++bk) {
        const float zr = rlane(p0, bk), zi = rlane(p1, bk), kr = rlane(p2, bk);
        const float ki = rlane(p0, 32 + bk), qr = rlane(p1, 32 + bk), qi = rlane(p2, 32 + bk);
        const float sr = Sre[bk], si = Sim[bk];
        const float nr = fmaf(zr, sr, fmaf(-zi, si, kr * vcur));
        const float ni = fmaf(zr, si, fmaf(zi, sr, ki * vcur));
        Sre[bk] = nr; Sim[bk] = ni;
        y = fmaf(qr, nr, fmaf(qi, ni, y));
      }
      yi[((size_t)cid * 64 + t) * 64 + lane] = y;
    }
    __syncthreads();
  }
#pragma unroll
  for (int bk = 0; bk < 32; ++bk)
    *(float2*)&Tg[(((size_t)cid * 32 + bk) * 64 + lane) * 2] = make_float2(Sre[bk], Sim[bk]);
  if (lane < 32) {
    const float de = __expf(-cumL);
    float dsn, dcs;
    __sincosf(cumT, &dsn, &dcs);
    Dg[((size_t)cid * 32 + j) * 2 + 0] = de * dcs;
    Dg[((size_t)cid * 32 + j) * 2 + 1] = de * dsn;
  }
}

// ------------------------------- pass B (scan) ------------------------------
// C_in[0]=0; C_in[c] = D[c-1]*C_in[c-1] + T[c-1]. 64 blocks (bh) x 4 waves (bk/8)
__global__ __launch_bounds__(256) void scanB_kernel(
    const float* __restrict__ Tg, const float* __restrict__ Dg, float* __restrict__ Cg) {
  const int bh = blockIdx.x;
  const int tid = threadIdx.x, wv = tid >> 6, lane = tid & 63;
  const int bkb = wv * 8;
  float Cr[8], Ci[8];
#pragma unroll
  for (int i = 0; i < 8; ++i) { Cr[i] = 0.f; Ci[i] = 0.f; }
  for (int c = 0; c < 32; ++c) {
    const size_t cid = (size_t)bh * 32 + c;
    float2 tv[8], dv[8];
#pragma unroll
    for (int i = 0; i < 8; ++i) {
      tv[i] = *(const float2*)&Tg[((cid * 32 + bkb + i) * 64 + lane) * 2];
      dv[i] = *(const float2*)&Dg[(cid * 32 + bkb + i) * 2];
    }
#pragma unroll
    for (int i = 0; i < 8; ++i) {
      *(float2*)&Cg[((cid * 32 + bkb + i) * 64 + lane) * 2] = make_float2(Cr[i], Ci[i]);
      const float nr = fmaf(dv[i].x, Cr[i], fmaf(-dv[i].y, Ci[i], tv[i].x));
      const float ni = fmaf(dv[i].x, Ci[i], fmaf(dv[i].y, Cr[i], tv[i].y));
      Cr[i] = nr; Ci[i] = ni;
    }
  }
}

// ------------------------------- pass C -------------------------------------
// y = y_intra + Re(qd . C_in); write attn bf16 [m][h*64+v]
__global__ __launch_bounds__(64) void passC_kernel(
    const float* __restrict__ yi, const float* __restrict__ Qg,
    const float* __restrict__ Cg, unsigned short* __restrict__ attn) {
  const int c = blockIdx.x, bh = blockIdx.y;
  const int b = bh >> 4, h = bh & 15;
  const int cid = bh * 32 + c;
  const int lane = threadIdx.x;
  float Cr[32], Ci[32];
#pragma unroll
  for (int bk = 0; bk < 32; ++bk) {
    const float2 cc = *(const float2*)&Cg[(((size_t)cid * 32 + bk) * 64 + lane) * 2];
    Cr[bk] = cc.x; Ci[bk] = cc.y;
  }
  const int m0 = b * 2048 + c * 64;
  for (int t = 0; t < 64; ++t) {
    const float pa = Qg[((size_t)cid * 64 + t) * 64 + lane];
    float y = yi[((size_t)cid * 64 + t) * 64 + lane];
#pragma unroll
    for (int bk = 0; bk < 32; ++bk) {
      const float ar = rlane(pa, bk), ai = rlane(pa, 32 + bk);
      y = fmaf(ar, Cr[bk], y);
      y = fmaf(-ai, Ci[bk], y);
    }
    attn[(size_t)(m0 + t) * 1024 + h * 64 + lane] = f2bf(y);
  }
}

// ---------------------------------------------------------------------------
extern "C" void kernel_launch(void* const* d_in, const int* in_sizes, int n_in,
                              void* d_out, int out_size, void* d_ws, size_t ws_size,
                              hipStream_t stream) {
  const float* x   = (const float*)d_in[0];
  const float* Wq  = (const float*)d_in[1];
  const float* bq  = (const float*)d_in[2];
  const float* Wk  = (const float*)d_in[3];
  const float* bk_ = (const float*)d_in[4];
  const float* Wv  = (const float*)d_in[5];
  const float* bv  = (const float*)d_in[6];
  const float* Wo  = (const float*)d_in[7];
  const float* bo  = (const float*)d_in[8];
  const float* n1g = (const float*)d_in[9];
  const float* n1b = (const float*)d_in[10];
  const float* n2g = (const float*)d_in[11];
  const float* n2b = (const float*)d_in[12];
  const float* thb = (const float*)d_in[13];
  const float* tw1 = (const float*)d_in[14];
  const float* tw2 = (const float*)d_in[15];
  const float* lamb= (const float*)d_in[16];
  const float* eta = (const float*)d_in[17];
  const float* Wf1 = (const float*)d_in[18];
  const float* bf1 = (const float*)d_in[19];
  const float* Wf2 = (const float*)d_in[20];
  const float* bf2 = (const float*)d_in[21];

  char* ws = (char*)d_ws;
  size_t off = 0;
  auto alloc = [&](size_t bytes) {
    size_t r = off;
    off += (bytes + 255) & ~(size_t)255;
    return r;
  };
  unsigned short* WCAT = (unsigned short*)(ws + alloc(3200ull * 1024 * 2));
  unsigned short* WOT  = (unsigned short*)(ws + alloc(1024ull * 1024 * 2));
  unsigned short* WF1T = (unsigned short*)(ws + alloc(4096ull * 1024 * 2));
  unsigned short* WF2T = (unsigned short*)(ws + alloc(1024ull * 4096 * 2));
  float* BIASC = (float*)(ws + alloc(3200ull * 4));
  unsigned short* XN = (unsigned short*)(ws + alloc(8192ull * 1024 * 2));  // also H (ln2 out)
  char* QKVbase = ws + alloc(8192ull * 3200 * 4);
  float* QKV = (float*)QKVbase;                                 // qkv+lora1 fp32
  unsigned short* GBUF = (unsigned short*)QKVbase;              // FFN1 out (aliases, after passA)
  float* CG = (float*)(QKVbase + 8192ull * 4096 * 2);           // scan out (aliases tail)
  float* THETA = (float*)(ws + alloc(8192ull * 512 * 4));       // also ATTN bf16 (after passA)
  unsigned short* ATTN = (unsigned short*)THETA;
  float* YI = (float*)(ws + alloc(2048ull * 64 * 64 * 4));      // also X1 (after passC)
  float* X1 = YI;
  float* QG = (float*)(ws + alloc(2048ull * 64 * 64 * 4));
  float* TG = (float*)(ws + alloc(2048ull * 32 * 64 * 2 * 4));
  float* DG = (float*)(ws + alloc(2048ull * 32 * 2 * 4));

  if (ws_size < off) {  // distinctive failure signature if workspace too small
    fill_kernel<<<dim3((out_size + 255) / 256), dim3(256), 0, stream>>>((float*)d_out, 12345.0f, out_size);
    return;
  }

  const dim3 b256(256), b64(64), b32x8(32, 8);

  // weight prep
  prep_wcat<<<dim3(100, 32), b32x8, 0, stream>>>(Wq, Wk, Wv, tw1, WCAT);
  transpose_bf16<<<dim3(32, 32), b32x8, 0, stream>>>(Wo, WOT, 1024, 1024);
  transpose_bf16<<<dim3(128, 32), b32x8, 0, stream>>>(Wf1, WF1T, 1024, 4096);
  transpose_bf16<<<dim3(32, 128), b32x8, 0, stream>>>(Wf2, WF2T, 4096, 1024);
  biascat_kernel<<<dim3(13), b256, 0, stream>>>(bq, bk_, bv, BIASC);

  // LN1 -> xn (bf16)
  ln_kernel<<<dim3(8192), b256, 0, stream>>>(x, n1g, n1b, XN);
  // QKV + lora1: [8192,3200] fp32
  gemm_kernel<0><<<dim3(25, 64), b256, 0, stream>>>(XN, WCAT, BIASC, nullptr, QKV, 3200, 1024);
  // lora2 -> theta (clipped)
  lora2_kernel<<<dim3(256), b256, 0, stream>>>(QKV, tw2, thb, THETA);
  // attention passes
  passA_kernel<<<dim3(32, 64), b64, 0, stream>>>(QKV, THETA, lamb, eta, YI, QG, TG, DG);
  scanB_kernel<<<dim3(64), b256, 0, stream>>>(TG, DG, CG);
  passC_kernel<<<dim3(32, 64), b64, 0, stream>>>(YI, QG, CG, ATTN);
  // x1 = x + attn@Wo + bo
  gemm_kernel<1><<<dim3(8, 64), b256, 0, stream>>>(ATTN, WOT, bo, x, X1, 1024, 1024);
  // LN2 -> h (bf16)
  ln_kernel<<<dim3(8192), b256, 0, stream>>>(X1, n2g, n2b, XN);
  // FFN1: g = gelu(h@Wf1 + bf1) (bf16)
  gemm_kernel<2><<<dim3(32, 64), b256, 0, stream>>>(XN, WF1T, bf1, nullptr, GBUF, 4096, 1024);
  // FFN2: out = x1 + g@Wf2 + bf2 (fp32)
  gemm_kernel<1><<<dim3(8, 64), b256, 0, stream>>>(GBUF, WF2T, bf2, X1, d_out, 1024, 4096);
}